// Round 6
// baseline (431.900 us; speedup 1.0000x reference)
//
#include <hip/hip_runtime.h>
#include <hip/hip_bf16.h>
#include <stdint.h>

typedef unsigned short u16;
typedef __attribute__((ext_vector_type(8))) short bf16x8;
typedef __attribute__((ext_vector_type(4))) float f32x4;
typedef __attribute__((ext_vector_type(16))) float f32x16;

static __device__ inline u16 f2bf(float f) {
  union { float f; uint32_t u; } v; v.f = f;
  uint32_t u = v.u;
  u += 0x7fffu + ((u >> 16) & 1);   // RNE
  return (u16)(u >> 16);
}

// fast 2^x -> single v_exp_f32
static __device__ inline float fast_exp2(float x) {
#if __has_builtin(__builtin_amdgcn_exp2f)
  return __builtin_amdgcn_exp2f(x);
#else
  return __expf(x * 0.6931471805599453f);
#endif
}

// pack two fp32 -> packed bf16x2
static __device__ inline uint32_t pack_bf16(float lo, float hi) {
#if __has_builtin(__builtin_amdgcn_cvt_pk_bf16_f32)
  typedef __attribute__((ext_vector_type(2))) __bf16 bf16x2_t;
  bf16x2_t r = __builtin_amdgcn_cvt_pk_bf16_f32(lo, hi);
  union { bf16x2_t v; uint32_t u; } c; c.v = r;
  return c.u;
#else
  union { float f; uint32_t u; } a, b;
  a.f = lo; b.f = hi;
  uint32_t ua = a.u + 0x8000u;
  uint32_t ub = b.u + 0x8000u;
  return __builtin_amdgcn_perm(ub, ua, 0x07060302u);
#endif
}

// async global->LDS, 16B per lane; LDS dest must be lane-contiguous (base + lane*16)
static __device__ __forceinline__ void load_lds_128(const u16* g, u16* l) {
  __builtin_amdgcn_global_load_lds((const __attribute__((address_space(1))) void*)g,
                                   (__attribute__((address_space(3))) void*)l,
                                   16, 0, 0);
}

// ---------------- cast z fp32 -> bf16 ----------------
__global__ __launch_bounds__(256) void cast_bf16_kernel(const float* __restrict__ src,
                                                        u16* __restrict__ dst, int n4) {
  int i = blockIdx.x * 256 + threadIdx.x;
  if (i < n4) {
    float4 v = reinterpret_cast<const float4*>(src)[i];
    uint2 o;
    o.x = pack_bf16(v.x, v.y);
    o.y = pack_bf16(v.z, v.w);
    reinterpret_cast<uint2*>(dst)[i] = o;
  }
}

// ---------------- weights: transpose + cast (Bt[n][k] = W[k][n]) ----------------
__global__ __launch_bounds__(256) void wtrans_kernel(const float* __restrict__ wq,
                                                     const float* __restrict__ wk,
                                                     const float* __restrict__ wv,
                                                     const float* __restrict__ wo,
                                                     u16* __restrict__ bqkv,
                                                     u16* __restrict__ wot) {
  int z = blockIdx.z;
  const float* src = (z == 0) ? wq : (z == 1) ? wk : (z == 2) ? wv : wo;
  u16* dst = (z < 3) ? (bqkv + (size_t)z * 1024 * 1024) : wot;
  __shared__ float tile[32][33];
  int c0 = blockIdx.x * 32, r0 = blockIdx.y * 32;
  int tx = threadIdx.x, ty = threadIdx.y;
#pragma unroll
  for (int i = 0; i < 32; i += 8)
    tile[ty + i][tx] = src[(size_t)(r0 + ty + i) * 1024 + c0 + tx];
  __syncthreads();
#pragma unroll
  for (int i = 0; i < 32; i += 8)
    dst[(size_t)(c0 + ty + i) * 1024 + r0 + tx] = f2bf(tile[tx][ty + i]);
}

// ---------------- GEMM (m97 structure): C[M,N] = A[M,1024] @ Bt[N,1024]^T ----------------
// LDS tiles unpadded [128][32], staged via global_load_lds width=16.
// MODE 0: N=3072 -> Q,K bf16 [bh][tok][64] (Q pre-scaled 0.125*log2e), V^T [bh][64][tok]
// MODE 1: N=1024, write fp32 + bias
template <int MODE>
__global__ __launch_bounds__(256) void gemm_bt_kernel(
    const u16* __restrict__ A, const u16* __restrict__ Bt,
    u16* __restrict__ outQ, u16* __restrict__ outK, u16* __restrict__ outVt,
    float* __restrict__ outC, const float* __restrict__ bias) {
  const int Kd = 1024;
  const int n0 = blockIdx.x * 128;
  const int m0 = blockIdx.y * 128;
  __shared__ __align__(16) u16 Asm[128 * 32];   // 8 KB, stride 32 (64B rows)
  __shared__ __align__(16) u16 Bsm[128 * 32];
  const int tid = threadIdx.x;
  const int wave = tid >> 6, lane = tid & 63;
  const int quad = lane >> 4, l15 = lane & 15;
  const int wm = (wave >> 1) * 64, wn = (wave & 1) * 64;

  const int c0 = wave * 128 + lane;
  const int c1 = c0 + 64;
  const int r0 = c0 >> 2, p0 = (c0 & 3) * 8;
  const int r1 = c1 >> 2, p1 = (c1 & 3) * 8;

  const u16* Ab = A + (size_t)m0 * Kd;
  const u16* Bb = Bt + (size_t)n0 * Kd;

  f32x4 acc[4][4] = {};

  for (int k0 = 0; k0 < Kd; k0 += 32) {
    __syncthreads();
    load_lds_128(Ab + (size_t)r0 * Kd + k0 + p0, Asm + c0 * 8);
    load_lds_128(Ab + (size_t)r1 * Kd + k0 + p1, Asm + c1 * 8);
    load_lds_128(Bb + (size_t)r0 * Kd + k0 + p0, Bsm + c0 * 8);
    load_lds_128(Bb + (size_t)r1 * Kd + k0 + p1, Bsm + c1 * 8);
    __syncthreads();
    bf16x8 af[4], bf[4];
#pragma unroll
    for (int i = 0; i < 4; i++)
      af[i] = *reinterpret_cast<const bf16x8*>(Asm + (wm + i * 16 + l15) * 32 + quad * 8);
#pragma unroll
    for (int i = 0; i < 4; i++)
      bf[i] = *reinterpret_cast<const bf16x8*>(Bsm + (wn + i * 16 + l15) * 32 + quad * 8);
#pragma unroll
    for (int mi = 0; mi < 4; mi++)
#pragma unroll
      for (int ni = 0; ni < 4; ni++)
        acc[mi][ni] = __builtin_amdgcn_mfma_f32_16x16x32_bf16(af[mi], bf[ni], acc[mi][ni], 0, 0, 0);
  }

  if (MODE == 0) {
    const int which = (n0 + wn) >> 10;          // uniform per wave (tile never crosses 1024)
#pragma unroll
    for (int mi = 0; mi < 4; mi++)
#pragma unroll
      for (int ni = 0; ni < 4; ni++) {
        int n = n0 + wn + ni * 16 + l15;
        int hn = n & 1023;
        int h = hn >> 6, dim = hn & 63;
        if (which == 2) {
          int m = m0 + wm + mi * 16 + quad * 4;
          int b = m >> 11, tok = m & 2047;
          uint2 pk;
          pk.x = pack_bf16(acc[mi][ni][0], acc[mi][ni][1]);
          pk.y = pack_bf16(acc[mi][ni][2], acc[mi][ni][3]);
          *reinterpret_cast<uint2*>(outVt + ((size_t)(b * 16 + h) * 64 + dim) * 2048 + tok) = pk;
        } else {
          u16* dst = (which == 0) ? outQ : outK;
          float qscale = (which == 0) ? 0.1803368801111204f : 1.0f; // 0.125*log2(e)
#pragma unroll
          for (int r = 0; r < 4; r++) {
            int m = m0 + wm + mi * 16 + quad * 4 + r;
            int b = m >> 11, tok = m & 2047;
            dst[(((size_t)(b * 16 + h)) * 2048 + tok) * 64 + dim] = f2bf(acc[mi][ni][r] * qscale);
          }
        }
      }
  } else {
#pragma unroll
    for (int mi = 0; mi < 4; mi++)
#pragma unroll
      for (int ni = 0; ni < 4; ni++) {
        int n = n0 + wn + ni * 16 + l15;
        float bv = bias[n];
#pragma unroll
        for (int r = 0; r < 4; r++) {
          int m = m0 + wm + mi * 16 + quad * 4 + r;
          outC[(size_t)m * 1024 + n] = acc[mi][ni][r] + bv;
        }
      }
  }
}

// ---------------- flash attention per (b,h): barrier-free, direct-global fragments ----
// Q,K: [bh][2048][64] bf16 (Q pre-scaled 0.125*log2e) ; Vt: [bh][64][2048] bf16
// out: [b][tok][h*64+dim] bf16. 128 queries/block, 32/wave, 32x32 MFMA.
// All K/V fragments are contiguous 16B chunks in global -> load directly to VGPRs,
// no LDS staging, NO __syncthreads anywhere. LDS holds only wave-private P.
// grid (64,16): bh = blockIdx.x so all q-blocks of a bh share an XCD (L2 affinity).
__global__ __launch_bounds__(256, 4) void attn_kernel(const u16* __restrict__ Q,
                                                      const u16* __restrict__ K,
                                                      const u16* __restrict__ Vt,
                                                      u16* __restrict__ Oout) {
  const int bh = blockIdx.x;
  const int q0 = blockIdx.y * 128;
  const int tid = threadIdx.x;
  const int wave = tid >> 6, lane = tid & 63;
  const int l31 = lane & 31, h = lane >> 5;

  __shared__ __align__(16) u16 Ps[4][32 * 72];   // per-wave P tile [query 32][key 72]

  const u16* Qg = Q + ((size_t)bh * 2048 + q0 + wave * 32) * 64;
  const u16* Kg = K + (size_t)bh * 2048 * 64;
  const u16* Vg = Vt + (size_t)bh * 64 * 2048;

  // Q fragments straight from global (once)
  bf16x8 qf[4];
#pragma unroll
  for (int dc = 0; dc < 4; dc++)
    qf[dc] = *reinterpret_cast<const bf16x8*>(Qg + (size_t)l31 * 64 + dc * 16 + h * 8);

  u16* Pw = &Ps[wave][0];
  float ls0 = 0.f, ls1 = 0.f, ls2 = 0.f, ls3 = 0.f;
  f32x16 oacc[2] = {};

  for (int kt = 0; kt < 2048; kt += 64) {
    // ---- K fragments for both 32-key halves (8 x 16B loads, independent) ----
    bf16x8 kf0[4], kf1[4];
    const u16* Krow0 = Kg + (size_t)(kt + l31) * 64 + h * 8;
    const u16* Krow1 = Krow0 + 32 * 64;
#pragma unroll
    for (int dc = 0; dc < 4; dc++) {
      kf0[dc] = *reinterpret_cast<const bf16x8*>(Krow0 + dc * 16);
      kf1[dc] = *reinterpret_cast<const bf16x8*>(Krow1 + dc * 16);
    }

    // ---- S^T = K Q^T for both halves ----
    f32x16 s0 = {}, s1 = {};
#pragma unroll
    for (int dc = 0; dc < 4; dc++) {
      s0 = __builtin_amdgcn_mfma_f32_32x32x16_bf16(kf0[dc], qf[dc], s0, 0, 0, 0);
      s1 = __builtin_amdgcn_mfma_f32_32x32x16_bf16(kf1[dc], qf[dc], s1, 0, 0, 0);
    }

    // ---- V fragments issued now; softmax VALU below covers their latency ----
    bf16x8 vf0[4], vf1[4];
    const u16* Vrow0 = Vg + (size_t)l31 * 2048 + kt + h * 8;
    const u16* Vrow1 = Vrow0 + 32 * 2048;
#pragma unroll
    for (int kc = 0; kc < 4; kc++) {
      vf0[kc] = *reinterpret_cast<const bf16x8*>(Vrow0 + kc * 16);
      vf1[kc] = *reinterpret_cast<const bf16x8*>(Vrow1 + kc * 16);
    }

    // ---- softmax (no-max, Q pre-scaled so exp2 is the softmax exp) + P to LDS ----
#pragma unroll
    for (int kb = 0; kb < 2; kb++) {
      const f32x16& s = kb ? s1 : s0;
      float p[16];
#pragma unroll
      for (int i = 0; i < 16; i++) p[i] = fast_exp2(s[i]);
#pragma unroll
      for (int i = 0; i < 16; i += 4) {
        ls0 += p[i]; ls1 += p[i + 1]; ls2 += p[i + 2]; ls3 += p[i + 3];
      }
#pragma unroll
      for (int rg = 0; rg < 4; rg++) {
        uint2 pk;
        pk.x = pack_bf16(p[rg * 4 + 0], p[rg * 4 + 1]);
        pk.y = pack_bf16(p[rg * 4 + 2], p[rg * 4 + 3]);
        *reinterpret_cast<uint2*>(&Pw[l31 * 72 + kb * 32 + rg * 8 + h * 4]) = pk;
      }
    }
    // wave-private P: same-wave DS ordering via lgkmcnt, no barrier

    // ---- PV ----
    bf16x8 pfr[4];
#pragma unroll
    for (int kc = 0; kc < 4; kc++)
      pfr[kc] = *reinterpret_cast<const bf16x8*>(&Pw[l31 * 72 + kc * 16 + h * 8]);
#pragma unroll
    for (int kc = 0; kc < 4; kc++) {
      oacc[0] = __builtin_amdgcn_mfma_f32_32x32x16_bf16(pfr[kc], vf0[kc], oacc[0], 0, 0, 0);
      oacc[1] = __builtin_amdgcn_mfma_f32_32x32x16_bf16(pfr[kc], vf1[kc], oacc[1], 0, 0, 0);
    }
  }

  float lsum = (ls0 + ls1) + (ls2 + ls3);
  lsum += __shfl_xor(lsum, 32, 64);   // combine key-halves (mod-8 coverage split)
  float inv[16];
#pragma unroll
  for (int reg = 0; reg < 16; reg++) {
    int qq = (reg & 3) + 8 * (reg >> 2) + 4 * h;
    int lv = __builtin_amdgcn_ds_bpermute(qq << 2, __float_as_int(lsum));
    inv[reg] = __builtin_amdgcn_rcpf(__int_as_float(lv));
  }

  const int b = bh >> 4, hd = bh & 15;
  u16* dst = Oout + (size_t)b * 2048 * 1024 + (size_t)hd * 64;
#pragma unroll
  for (int dt = 0; dt < 2; dt++)
#pragma unroll
    for (int reg = 0; reg < 16; reg++) {
      int qq = q0 + wave * 32 + (reg & 3) + 8 * (reg >> 2) + 4 * h;
      dst[(size_t)qq * 1024 + dt * 32 + l31] = f2bf(oacc[dt][reg] * inv[reg]);
    }
}

extern "C" void kernel_launch(void* const* d_in, const int* in_sizes, int n_in,
                              void* d_out, int out_size, void* d_ws, size_t ws_size,
                              hipStream_t stream) {
  (void)in_sizes; (void)n_in; (void)out_size; (void)ws_size;
  const float* z  = (const float*)d_in[0];
  const float* wq = (const float*)d_in[1];
  const float* wk = (const float*)d_in[2];
  const float* wv = (const float*)d_in[3];
  const float* wo = (const float*)d_in[4];
  const float* bo = (const float*)d_in[5];
  float* out = (float*)d_out;

  // workspace layout (72 MiB):
  char* ws = (char*)d_ws;
  u16* zb   = (u16*)(ws);                          // 16 MiB  z bf16 [8192][1024]; reused as attn_out
  u16* bqkv = (u16*)(ws + (16ull << 20));          // 6 MiB   W_qkv^T [3072][1024]
  u16* wot  = (u16*)(ws + (22ull << 20));          // 2 MiB   W_o^T   [1024][1024]
  u16* Qb   = (u16*)(ws + (24ull << 20));          // 16 MiB  [64][2048][64]
  u16* Kb   = (u16*)(ws + (40ull << 20));          // 16 MiB  [64][2048][64]
  u16* Vtb  = (u16*)(ws + (56ull << 20));          // 16 MiB  [64][64][2048] (written by GEMM)
  u16* Ob   = zb;                                  // attn_out [8192][1024]

  cast_bf16_kernel<<<8192, 256, 0, stream>>>(z, zb, 2097152);
  wtrans_kernel<<<dim3(32, 32, 4), dim3(32, 8), 0, stream>>>(wq, wk, wv, wo, bqkv, wot);
  gemm_bt_kernel<0><<<dim3(24, 64), 256, 0, stream>>>(zb, bqkv, Qb, Kb, Vtb, nullptr, nullptr);
  attn_kernel<<<dim3(64, 16), 256, 0, stream>>>(Qb, Kb, Vtb, Ob);
  gemm_bt_kernel<1><<<dim3(8, 64), 256, 0, stream>>>(Ob, wot, nullptr, nullptr, nullptr, out, bo);
}

// Round 7
// 297.774 us; speedup vs baseline: 1.4504x; 1.4504x over previous
//
#include <hip/hip_runtime.h>
#include <hip/hip_bf16.h>
#include <stdint.h>

typedef unsigned short u16;
typedef __attribute__((ext_vector_type(8))) short bf16x8;
typedef __attribute__((ext_vector_type(4))) float f32x4;
typedef __attribute__((ext_vector_type(16))) float f32x16;

static __device__ inline u16 f2bf(float f) {
  union { float f; uint32_t u; } v; v.f = f;
  uint32_t u = v.u;
  u += 0x7fffu + ((u >> 16) & 1);   // RNE
  return (u16)(u >> 16);
}

// fast 2^x -> single v_exp_f32
static __device__ inline float fast_exp2(float x) {
#if __has_builtin(__builtin_amdgcn_exp2f)
  return __builtin_amdgcn_exp2f(x);
#else
  return __expf(x * 0.6931471805599453f);
#endif
}

// pack two fp32 -> packed bf16x2
static __device__ inline uint32_t pack_bf16(float lo, float hi) {
#if __has_builtin(__builtin_amdgcn_cvt_pk_bf16_f32)
  typedef __attribute__((ext_vector_type(2))) __bf16 bf16x2_t;
  bf16x2_t r = __builtin_amdgcn_cvt_pk_bf16_f32(lo, hi);
  union { bf16x2_t v; uint32_t u; } c; c.v = r;
  return c.u;
#else
  union { float f; uint32_t u; } a, b;
  a.f = lo; b.f = hi;
  uint32_t ua = a.u + 0x8000u;
  uint32_t ub = b.u + 0x8000u;
  return __builtin_amdgcn_perm(ub, ua, 0x07060302u);
#endif
}

// async global->LDS, 16B per lane; LDS dest must be lane-contiguous (base + lane*16)
static __device__ __forceinline__ void load_lds_128(const u16* g, u16* l) {
  __builtin_amdgcn_global_load_lds((const __attribute__((address_space(1))) void*)g,
                                   (__attribute__((address_space(3))) void*)l,
                                   16, 0, 0);
}

// ---------------- cast z fp32 -> bf16 ----------------
__global__ __launch_bounds__(256) void cast_bf16_kernel(const float* __restrict__ src,
                                                        u16* __restrict__ dst, int n4) {
  int i = blockIdx.x * 256 + threadIdx.x;
  if (i < n4) {
    float4 v = reinterpret_cast<const float4*>(src)[i];
    uint2 o;
    o.x = pack_bf16(v.x, v.y);
    o.y = pack_bf16(v.z, v.w);
    reinterpret_cast<uint2*>(dst)[i] = o;
  }
}

// ---------------- weights: transpose + cast (Bt[n][k] = W[k][n]) ----------------
__global__ __launch_bounds__(256) void wtrans_kernel(const float* __restrict__ wq,
                                                     const float* __restrict__ wk,
                                                     const float* __restrict__ wv,
                                                     const float* __restrict__ wo,
                                                     u16* __restrict__ bqkv,
                                                     u16* __restrict__ wot) {
  int z = blockIdx.z;
  const float* src = (z == 0) ? wq : (z == 1) ? wk : (z == 2) ? wv : wo;
  u16* dst = (z < 3) ? (bqkv + (size_t)z * 1024 * 1024) : wot;
  __shared__ float tile[32][33];
  int c0 = blockIdx.x * 32, r0 = blockIdx.y * 32;
  int tx = threadIdx.x, ty = threadIdx.y;
#pragma unroll
  for (int i = 0; i < 32; i += 8)
    tile[ty + i][tx] = src[(size_t)(r0 + ty + i) * 1024 + c0 + tx];
  __syncthreads();
#pragma unroll
  for (int i = 0; i < 32; i += 8)
    dst[(size_t)(c0 + ty + i) * 1024 + r0 + tx] = f2bf(tile[tx][ty + i]);
}

// ---------------- GEMM (m97 structure): C[M,N] = A[M,1024] @ Bt[N,1024]^T ----------------
template <int MODE>
__global__ __launch_bounds__(256) void gemm_bt_kernel(
    const u16* __restrict__ A, const u16* __restrict__ Bt,
    u16* __restrict__ outQ, u16* __restrict__ outK, u16* __restrict__ outVt,
    float* __restrict__ outC, const float* __restrict__ bias) {
  const int Kd = 1024;
  const int n0 = blockIdx.x * 128;
  const int m0 = blockIdx.y * 128;
  __shared__ __align__(16) u16 Asm[128 * 32];
  __shared__ __align__(16) u16 Bsm[128 * 32];
  const int tid = threadIdx.x;
  const int wave = tid >> 6, lane = tid & 63;
  const int quad = lane >> 4, l15 = lane & 15;
  const int wm = (wave >> 1) * 64, wn = (wave & 1) * 64;

  const int c0 = wave * 128 + lane;
  const int c1 = c0 + 64;
  const int r0 = c0 >> 2, p0 = (c0 & 3) * 8;
  const int r1 = c1 >> 2, p1 = (c1 & 3) * 8;

  const u16* Ab = A + (size_t)m0 * Kd;
  const u16* Bb = Bt + (size_t)n0 * Kd;

  f32x4 acc[4][4] = {};

  for (int k0 = 0; k0 < Kd; k0 += 32) {
    __syncthreads();
    load_lds_128(Ab + (size_t)r0 * Kd + k0 + p0, Asm + c0 * 8);
    load_lds_128(Ab + (size_t)r1 * Kd + k0 + p1, Asm + c1 * 8);
    load_lds_128(Bb + (size_t)r0 * Kd + k0 + p0, Bsm + c0 * 8);
    load_lds_128(Bb + (size_t)r1 * Kd + k0 + p1, Bsm + c1 * 8);
    __syncthreads();
    bf16x8 af[4], bf[4];
#pragma unroll
    for (int i = 0; i < 4; i++)
      af[i] = *reinterpret_cast<const bf16x8*>(Asm + (wm + i * 16 + l15) * 32 + quad * 8);
#pragma unroll
    for (int i = 0; i < 4; i++)
      bf[i] = *reinterpret_cast<const bf16x8*>(Bsm + (wn + i * 16 + l15) * 32 + quad * 8);
#pragma unroll
    for (int mi = 0; mi < 4; mi++)
#pragma unroll
      for (int ni = 0; ni < 4; ni++)
        acc[mi][ni] = __builtin_amdgcn_mfma_f32_16x16x32_bf16(af[mi], bf[ni], acc[mi][ni], 0, 0, 0);
  }

  if (MODE == 0) {
    const int which = (n0 + wn) >> 10;
#pragma unroll
    for (int mi = 0; mi < 4; mi++)
#pragma unroll
      for (int ni = 0; ni < 4; ni++) {
        int n = n0 + wn + ni * 16 + l15;
        int hn = n & 1023;
        int h = hn >> 6, dim = hn & 63;
        if (which == 2) {
          int m = m0 + wm + mi * 16 + quad * 4;
          int b = m >> 11, tok = m & 2047;
          uint2 pk;
          pk.x = pack_bf16(acc[mi][ni][0], acc[mi][ni][1]);
          pk.y = pack_bf16(acc[mi][ni][2], acc[mi][ni][3]);
          *reinterpret_cast<uint2*>(outVt + ((size_t)(b * 16 + h) * 64 + dim) * 2048 + tok) = pk;
        } else {
          u16* dst = (which == 0) ? outQ : outK;
          float qscale = (which == 0) ? 0.1803368801111204f : 1.0f; // 0.125*log2(e)
#pragma unroll
          for (int r = 0; r < 4; r++) {
            int m = m0 + wm + mi * 16 + quad * 4 + r;
            int b = m >> 11, tok = m & 2047;
            dst[(((size_t)(b * 16 + h)) * 2048 + tok) * 64 + dim] = f2bf(acc[mi][ni][r] * qscale);
          }
        }
      }
  } else {
#pragma unroll
    for (int mi = 0; mi < 4; mi++)
#pragma unroll
      for (int ni = 0; ni < 4; ni++) {
        int n = n0 + wn + ni * 16 + l15;
        float bv = bias[n];
#pragma unroll
        for (int r = 0; r < 4; r++) {
          int m = m0 + wm + mi * 16 + quad * 4 + r;
          outC[(size_t)m * 1024 + n] = acc[mi][ni][r] + bv;
        }
      }
  }
}

// ---------------- flash attention: single-barrier dbuf, swizzled LDS, reg-P ----------
// Q,K: [bh][2048][64] bf16 (Q pre-scaled 0.125*log2e) ; Vt: [bh][64][2048] bf16
// out: [b][tok][h*64+dim] bf16. 128 queries/block, 32/wave, 32x32 MFMA.
// LDS: XOR-swizzled [2][64][64] K and V tiles (chunk' = chunk ^ (row&7)), staged by
// global_load_lds (swizzle applied on global source addr; LDS dest lane-contiguous).
// P never touches LDS: O^T = V^T(A) x P^T(B); B-frags built from S^T C-layout regs
// via one shfl_xor(32) pair per 32 keys. One __syncthreads per tile.
__global__ __launch_bounds__(256, 3) void attn_kernel(const u16* __restrict__ Q,
                                                      const u16* __restrict__ K,
                                                      const u16* __restrict__ Vt,
                                                      u16* __restrict__ Oout) {
  const int bh = blockIdx.x;
  const int q0 = blockIdx.y * 128;
  const int tid = threadIdx.x;
  const int wave = tid >> 6, lane = tid & 63;
  const int l31 = lane & 31, h = lane >> 5;
  const int e = l31 & 7;

  __shared__ __align__(16) u16 Kb2[2][4096];   // [64 rows][64], swizzled chunks
  __shared__ __align__(16) u16 Vb2[2][4096];

  const u16* Qg = Q + ((size_t)bh * 2048 + q0 + wave * 32) * 64;
  const u16* Kg = K + (size_t)bh * 2048 * 64;
  const u16* Vg = Vt + (size_t)bh * 64 * 2048;

  // Q fragments direct from global (once per kernel)
  bf16x8 qf[4];
#pragma unroll
  for (int dc = 0; dc < 4; dc++)
    qf[dc] = *reinterpret_cast<const bf16x8*>(Qg + (size_t)l31 * 64 + dc * 16 + h * 8);

  // staging: chunk s -> LDS slot s (lane-contig), global chunk = (s&7)^(row&7)
  const int s0 = tid, s1 = tid + 256;
  const int sr0 = s0 >> 3, sg0 = ((s0 & 7) ^ (sr0 & 7)) * 8;
  const int sr1 = s1 >> 3, sg1 = ((s1 & 7) ^ (sr1 & 7)) * 8;

  load_lds_128(Kg + (size_t)sr0 * 64 + sg0, &Kb2[0][s0 * 8]);
  load_lds_128(Kg + (size_t)sr1 * 64 + sg1, &Kb2[0][s1 * 8]);
  load_lds_128(Vg + (size_t)sr0 * 2048 + sg0, &Vb2[0][s0 * 8]);
  load_lds_128(Vg + (size_t)sr1 * 2048 + sg1, &Vb2[0][s1 * 8]);
  __syncthreads();   // tile 0 resident

  float ls0 = 0.f, ls1 = 0.f;
  f32x16 oacc[2] = {};
  int cur = 0;

  for (int kt = 0; kt < 2048; kt += 64) {
    const u16* uK = &Kb2[cur][0];
    const u16* uV = &Vb2[cur][0];

    // ---- fragment reads (conflict-free via swizzle) ----
    bf16x8 kfr[2][4], vfr[2][2][2];
#pragma unroll
    for (int kb = 0; kb < 2; kb++)
#pragma unroll
      for (int dc = 0; dc < 4; dc++)
        kfr[kb][dc] = *reinterpret_cast<const bf16x8*>(
            uK + (kb * 32 + l31) * 64 + (((2 * dc + h) ^ e) * 8));
#pragma unroll
    for (int dt = 0; dt < 2; dt++)
#pragma unroll
      for (int kb = 0; kb < 2; kb++)
#pragma unroll
        for (int kc = 0; kc < 2; kc++)
          vfr[dt][kb][kc] = *reinterpret_cast<const bf16x8*>(
              uV + (dt * 32 + l31) * 64 + (((4 * kb + 2 * kc + h) ^ e) * 8));

    // ---- async DMA next tile into other buffer (drained at loop-end barrier) ----
    if (kt + 64 < 2048) {
      const int nb = cur ^ 1;
      load_lds_128(Kg + (size_t)(kt + 64 + sr0) * 64 + sg0, &Kb2[nb][s0 * 8]);
      load_lds_128(Kg + (size_t)(kt + 64 + sr1) * 64 + sg1, &Kb2[nb][s1 * 8]);
      load_lds_128(Vg + (size_t)sr0 * 2048 + kt + 64 + sg0, &Vb2[nb][s0 * 8]);
      load_lds_128(Vg + (size_t)sr1 * 2048 + kt + 64 + sg1, &Vb2[nb][s1 * 8]);
    }

    // ---- per 32-key half: S^T, softmax, reg-exchange, PV ----
#pragma unroll
    for (int kb = 0; kb < 2; kb++) {
      f32x16 s = {};
#pragma unroll
      for (int dc = 0; dc < 4; dc++)
        s = __builtin_amdgcn_mfma_f32_32x32x16_bf16(kfr[kb][dc], qf[dc], s, 0, 0, 0);
      // lane (q=l31,h) reg r holds key (r&3)+8*(r>>2)+4h (+32kb)
      float p[16];
#pragma unroll
      for (int i = 0; i < 16; i++) p[i] = fast_exp2(s[i]);
#pragma unroll
      for (int i = 0; i < 16; i += 2) { ls0 += p[i]; ls1 += p[i + 1]; }
      uint2 pk[4];
#pragma unroll
      for (int rq = 0; rq < 4; rq++) {
        pk[rq].x = pack_bf16(p[rq * 4 + 0], p[rq * 4 + 1]);
        pk[rq].y = pack_bf16(p[rq * 4 + 2], p[rq * 4 + 3]);
      }
      // B-frag keys (within kb): kc0 needs {8h..8h+7} = h? [partner pk1, own pk1]
      //                                               : [own pk0, partner pk0]
      //            kc1 needs {16+8h..+7}          = h? [partner pk3, own pk3]
      //                                               : [own pk2, partner pk2]
      // exchange: send h? pk0:pk1 (serves kc0), h? pk2:pk3 (serves kc1)
      uint2 snd0 = h ? pk[0] : pk[1];
      uint2 snd1 = h ? pk[2] : pk[3];
      uint2 rx0, rx1;
      rx0.x = __shfl_xor((int)snd0.x, 32, 64); rx0.y = __shfl_xor((int)snd0.y, 32, 64);
      rx1.x = __shfl_xor((int)snd1.x, 32, 64); rx1.y = __shfl_xor((int)snd1.y, 32, 64);
      uint4 b0, b1;
      b0.x = h ? rx0.x : pk[0].x;  b0.y = h ? rx0.y : pk[0].y;
      b0.z = h ? pk[1].x : rx0.x;  b0.w = h ? pk[1].y : rx0.y;
      b1.x = h ? rx1.x : pk[2].x;  b1.y = h ? rx1.y : pk[2].y;
      b1.z = h ? pk[3].x : rx1.x;  b1.w = h ? pk[3].y : rx1.y;
      union { uint4 u; bf16x8 v; } bf0, bf1;
      bf0.u = b0; bf1.u = b1;
#pragma unroll
      for (int dt = 0; dt < 2; dt++) {
        oacc[dt] = __builtin_amdgcn_mfma_f32_32x32x16_bf16(vfr[dt][kb][0], bf0.v, oacc[dt], 0, 0, 0);
        oacc[dt] = __builtin_amdgcn_mfma_f32_32x32x16_bf16(vfr[dt][kb][1], bf1.v, oacc[dt], 0, 0, 0);
      }
    }

    __syncthreads();   // joins: frag reads done (lgkm), next-tile DMA done (vmcnt)
    cur ^= 1;
  }

  // per-lane row sum: own half + partner half
  float lsum = ls0 + ls1;
  lsum += __shfl_xor(lsum, 32, 64);
  float inv = __builtin_amdgcn_rcpf(lsum);

  // O^T layout: lane = q (l31), reg r = dim (r&3)+8*(r>>2)+4h+32dt
  const int b = bh >> 4, hd = bh & 15;
  u16* dst = Oout + (size_t)b * 2048 * 1024 + (size_t)hd * 64;
  const size_t qrow = (size_t)(q0 + wave * 32 + l31) * 1024;
#pragma unroll
  for (int dt = 0; dt < 2; dt++)
#pragma unroll
    for (int rq = 0; rq < 4; rq++) {
      uint2 o;
      o.x = pack_bf16(oacc[dt][rq * 4 + 0] * inv, oacc[dt][rq * 4 + 1] * inv);
      o.y = pack_bf16(oacc[dt][rq * 4 + 2] * inv, oacc[dt][rq * 4 + 3] * inv);
      *reinterpret_cast<uint2*>(dst + qrow + dt * 32 + rq * 8 + h * 4) = o;
    }
}

extern "C" void kernel_launch(void* const* d_in, const int* in_sizes, int n_in,
                              void* d_out, int out_size, void* d_ws, size_t ws_size,
                              hipStream_t stream) {
  (void)in_sizes; (void)n_in; (void)out_size; (void)ws_size;
  const float* z  = (const float*)d_in[0];
  const float* wq = (const float*)d_in[1];
  const float* wk = (const float*)d_in[2];
  const float* wv = (const float*)d_in[3];
  const float* wo = (const float*)d_in[4];
  const float* bo = (const float*)d_in[5];
  float* out = (float*)d_out;

  // workspace layout (72 MiB):
  char* ws = (char*)d_ws;
  u16* zb   = (u16*)(ws);                          // 16 MiB  z bf16 [8192][1024]; reused as attn_out
  u16* bqkv = (u16*)(ws + (16ull << 20));          // 6 MiB   W_qkv^T [3072][1024]
  u16* wot  = (u16*)(ws + (22ull << 20));          // 2 MiB   W_o^T   [1024][1024]
  u16* Qb   = (u16*)(ws + (24ull << 20));          // 16 MiB  [64][2048][64]
  u16* Kb   = (u16*)(ws + (40ull << 20));          // 16 MiB  [64][2048][64]
  u16* Vtb  = (u16*)(ws + (56ull << 20));          // 16 MiB  [64][64][2048] (written by GEMM)
  u16* Ob   = zb;                                  // attn_out [8192][1024]

  cast_bf16_kernel<<<8192, 256, 0, stream>>>(z, zb, 2097152);
  wtrans_kernel<<<dim3(32, 32, 4), dim3(32, 8), 0, stream>>>(wq, wk, wv, wo, bqkv, wot);
  gemm_bt_kernel<0><<<dim3(24, 64), 256, 0, stream>>>(zb, bqkv, Qb, Kb, Vtb, nullptr, nullptr);
  attn_kernel<<<dim3(64, 16), 256, 0, stream>>>(Qb, Kb, Vtb, Ob);
  gemm_bt_kernel<1><<<dim3(8, 64), 256, 0, stream>>>(Ob, wot, nullptr, nullptr, nullptr, out, bo);
}